// Round 1
// baseline (6393.811 us; speedup 1.0000x reference)
//
#include <hip/hip_runtime.h>
#include <stdint.h>

// VQ: bf16-MFMA candidate filter + exact np-fp32 rescore.
// Selection is bit-identical to the R4 kernel (absmax 32) as long as the
// exact winner lands in the candidate set, which the 1e-3 margin guarantees
// (worst-case |s_tilde - s_exact_unquantized| <= 5.9e-4, proof in session log).

#define NCODES 8192
#define DDIM   256
#define BT     65536

// legacy (R4) constants
#define TM     128
#define TN     128
#define NSEG   256
#define F4S    17

// new-path constants
#define CAPC   48
#define MARGIN 1e-3f
#define CHUNKS 64            // 8192 / 128 codes per chunk

typedef float  f32x4  __attribute__((ext_vector_type(4)));
typedef __bf16 bf16x8 __attribute__((ext_vector_type(8)));

#define GLDS16(g, l) __builtin_amdgcn_global_load_lds(                         \
    (const __attribute__((address_space(1))) void*)(g),                        \
    (__attribute__((address_space(3))) void*)(l), 16, 0, 0)
#define GLDS4(g, l) __builtin_amdgcn_global_load_lds(                          \
    (const __attribute__((address_space(1))) void*)(g),                        \
    (__attribute__((address_space(3))) void*)(l), 4, 0, 0)

// order-preserving float->uint map (for LDS atomicMin on scores)
__device__ __forceinline__ unsigned int fenc(float f) {
  unsigned int u = __float_as_uint(f);
  return (u & 0x80000000u) ? ~u : (u | 0x80000000u);
}
__device__ __forceinline__ float fdec(unsigned int u) {
  unsigned int v = (u & 0x80000000u) ? (u ^ 0x80000000u) : ~u;
  return __uint_as_float(v);
}

// numpy pairwise_sum (scalar path) for n=256 over p_i = fl32(x_i*x_i).
__device__ __forceinline__ float np_pairwise256_sq(const float4* __restrict__ row) {
#pragma clang fp contract(off)
  float half[2];
  #pragma unroll
  for (int h = 0; h < 2; h++) {
    float r0,r1,r2,r3,r4,r5,r6,r7;
    float4 q0 = row[h*32 + 0];
    float4 q1 = row[h*32 + 1];
    r0 = q0.x*q0.x; r1 = q0.y*q0.y; r2 = q0.z*q0.z; r3 = q0.w*q0.w;
    r4 = q1.x*q1.x; r5 = q1.y*q1.y; r6 = q1.z*q1.z; r7 = q1.w*q1.w;
    #pragma unroll
    for (int g = 1; g < 16; g++) {
      q0 = row[h*32 + g*2];
      q1 = row[h*32 + g*2 + 1];
      r0 += q0.x*q0.x; r1 += q0.y*q0.y; r2 += q0.z*q0.z; r3 += q0.w*q0.w;
      r4 += q1.x*q1.x; r5 += q1.y*q1.y; r6 += q1.z*q1.z; r7 += q1.w*q1.w;
    }
    half[h] = ((r0+r1) + (r2+r3)) + ((r4+r5) + (r6+r7));
  }
  return half[0] + half[1];
}

__global__ void vq_pre_a(const float* __restrict__ x, float* __restrict__ Astage) {
  const int t = blockIdx.x * 256 + threadIdx.x;
  Astage[t] = np_pairwise256_sq((const float4*)(x + (size_t)t * DDIM));
}

__global__ void vq_pre_c(const float* __restrict__ emb, float* __restrict__ Cws) {
  const int c = blockIdx.x * 256 + threadIdx.x;
  Cws[c] = np_pairwise256_sq((const float4*)(emb + (size_t)c * DDIM));
}

__global__ void vq_init(float* __restrict__ oloss) { *oloss = 0.0f; }

// emb fp32 -> bf16(RNE), stored XOR-swizzled so the filter's linear
// global_load_lds staging + swizzled ds_read_b128 is bank-conflict-free.
// Row layout: 512B per code; 16B block blk (k = blk*8..blk*8+7) stored at
// block index blk ^ (code&7).
__global__ void vq_pre_e(const float* __restrict__ emb, uint4* __restrict__ ebf) {
  const int g   = blockIdx.x * 256 + threadIdx.x;   // 262144 total
  const int c   = g >> 5;
  const int blk = g & 31;
  const float4* e4 = (const float4*)(emb + (size_t)c * DDIM);
  float4 f0 = e4[blk*2], f1 = e4[blk*2 + 1];
  union { unsigned short us[8]; uint4 v; } pk;
  pk.us[0] = __builtin_bit_cast(unsigned short, (__bf16)f0.x);
  pk.us[1] = __builtin_bit_cast(unsigned short, (__bf16)f0.y);
  pk.us[2] = __builtin_bit_cast(unsigned short, (__bf16)f0.z);
  pk.us[3] = __builtin_bit_cast(unsigned short, (__bf16)f0.w);
  pk.us[4] = __builtin_bit_cast(unsigned short, (__bf16)f1.x);
  pk.us[5] = __builtin_bit_cast(unsigned short, (__bf16)f1.y);
  pk.us[6] = __builtin_bit_cast(unsigned short, (__bf16)f1.z);
  pk.us[7] = __builtin_bit_cast(unsigned short, (__bf16)f1.w);
  ebf[(size_t)c * 32 + (blk ^ (c & 7))] = pk.v;
}

__device__ __forceinline__ void stage_chunk(const char* __restrict__ ebf,
                                            const float* __restrict__ Cws,
                                            int ch, char* ebuf_dst,
                                            float* cs_dst, int tid) {
  const char* src = ebf + (size_t)ch * 65536 + (size_t)tid * 16;
  char* dst = ebuf_dst + (size_t)tid * 16;
  #pragma unroll
  for (int i = 0; i < 8; ++i) GLDS16(src + i * 8192, dst + i * 8192);
  if (tid < 128)
    GLDS4((const char*)Cws + (size_t)ch * 512 + (size_t)tid * 4,
          (char*)cs_dst + (size_t)tid * 4);
}

// ---------------- MFMA candidate filter ----------------
// D[code][token] = emb_bf16 . x_bf16^T  (both row-major [*][256], gemm_bt form)
// block: 512 thr, 256 tokens; chunk: 128 codes; waves 2(code-half) x 4(token-quarter)
// wave tile 64 codes x 64 tokens; x K-resident in VGPR B-frags.
__global__ __launch_bounds__(512, 2)
void vq_filter(const float* __restrict__ x, const char* __restrict__ ebf,
               const float* __restrict__ Cws, int* __restrict__ cntG,
               int* __restrict__ candG) {
  __shared__ __align__(16) char ebuf[2][65536];   // 128 KiB double buffer
  __shared__ float Cs[3][128];                    // triple buffer (collect lags)
  __shared__ unsigned int umin[256];
  __shared__ int cntL[256];

  const int tid  = threadIdx.x;
  const int lane = tid & 63;
  const int wid  = tid >> 6;      // 0..7
  const int wm   = wid >> 2;      // 0..1  code half
  const int wn   = wid & 3;       // 0..3  token quarter
  const int l15  = lane & 15;
  const int lhi  = lane >> 4;     // 0..3
  const int tok0 = blockIdx.x * 256;

  if (tid < 256) { umin[tid] = 0xFFFFFFFFu; cntL[tid] = 0; }

  // stage chunk 0 (overlaps the x-fragment loads below)
  stage_chunk(ebf, Cws, 0, ebuf[0], Cs[0], tid);

  // B-frags: x[token][k] bf16, K-resident. frag reg j = k = kk*32 + lhi*8 + j.
  const float4* x4 = (const float4*)x;
  bf16x8 xb[4][8];
  #pragma unroll
  for (int n = 0; n < 4; ++n) {
    const size_t trow = (size_t)(tok0 + wn * 64 + n * 16 + l15) * 64;
    #pragma unroll
    for (int kk = 0; kk < 8; ++kk) {
      float4 f0 = x4[trow + kk * 8 + lhi * 2];
      float4 f1 = x4[trow + kk * 8 + lhi * 2 + 1];
      bf16x8 v;
      v[0] = (__bf16)f0.x; v[1] = (__bf16)f0.y; v[2] = (__bf16)f0.z; v[3] = (__bf16)f0.w;
      v[4] = (__bf16)f1.x; v[5] = (__bf16)f1.y; v[6] = (__bf16)f1.z; v[7] = (__bf16)f1.w;
      xb[n][kk] = v;
    }
  }
  __syncthreads();   // staging + init visible

  const f32x4 zf = {0.f, 0.f, 0.f, 0.f};

  for (int c = 0; c < CHUNKS; ++c) {
    // prefetch next chunk into the other buffers (wraps harmlessly at c=63)
    stage_chunk(ebf, Cws, (c + 1) & 63, ebuf[(c + 1) & 1], Cs[(c + 1) % 3], tid);

    const char* ecur = ebuf[c & 1];
    f32x4 acc[4][4];
    #pragma unroll
    for (int kk = 0; kk < 8; ++kk) {
      bf16x8 a[4];
      #pragma unroll
      for (int m = 0; m < 4; ++m) {
        const int row = wm * 64 + m * 16 + l15;
        const int blk = (kk * 4 + lhi) ^ (row & 7);
        a[m] = *(const bf16x8*)(ecur + row * 512 + blk * 16);
      }
      #pragma unroll
      for (int m = 0; m < 4; ++m)
        #pragma unroll
        for (int n = 0; n < 4; ++n)
          acc[m][n] = __builtin_amdgcn_mfma_f32_16x16x32_bf16(
              a[m], xb[n][kk], (kk == 0) ? zf : acc[m][n], 0, 0, 0);
    }

    // min phase: s~ = C - 2P, running per-token min via LDS atomicMin
    const float* Csc = Cs[c % 3];
    float cvals[4][4];
    #pragma unroll
    for (int m = 0; m < 4; ++m)
      #pragma unroll
      for (int r = 0; r < 4; ++r)
        cvals[m][r] = Csc[wm * 64 + m * 16 + lhi * 4 + r];

    #pragma unroll
    for (int n = 0; n < 4; ++n) {
      float mn = 1e30f;
      #pragma unroll
      for (int m = 0; m < 4; ++m)
        #pragma unroll
        for (int r = 0; r < 4; ++r)
          mn = fminf(mn, fmaf(-2.0f, acc[m][n][r], cvals[m][r]));
      atomicMin(&umin[wn * 64 + n * 16 + l15], fenc(mn));
    }

    __syncthreads();   // mins visible; next-chunk staging drained

    // collect phase: superset-safe (any observed umin >= final min)
    #pragma unroll
    for (int n = 0; n < 4; ++n) {
      const int t = wn * 64 + n * 16 + l15;
      const float thr = fdec(umin[t]) + MARGIN;
      #pragma unroll
      for (int m = 0; m < 4; ++m)
        #pragma unroll
        for (int r = 0; r < 4; ++r) {
          float s = fmaf(-2.0f, acc[m][n][r], cvals[m][r]);
          if (s <= thr) {
            int code = c * 128 + wm * 64 + m * 16 + lhi * 4 + r;
            int pos = atomicAdd(&cntL[t], 1);
            if (pos < CAPC) candG[(size_t)(tok0 + t) * CAPC + pos] = code;
          }
        }
    }
  }

  __syncthreads();
  if (tid < 256) cntG[tok0 + tid] = cntL[tid];
}

// ---------------- exact rescore + select + gather + loss ----------------
__global__ __launch_bounds__(256, 2)
void vq_rescore(const float* __restrict__ x, const float* __restrict__ emb,
                const float* __restrict__ Cws, const int* __restrict__ cntG,
                const int* __restrict__ candG, float* __restrict__ y,
                float* __restrict__ oidx, float* __restrict__ oloss) {
  __shared__ float xs[64 * 257];   // padded: chain reads conflict-free
  __shared__ float As[64];
  __shared__ int   idx_sh[64];
  __shared__ float red[4];

  const int tid  = threadIdx.x;
  const int tok0 = blockIdx.x * 64;
  const float4* x4g = (const float4*)x;
  const float4* e4g = (const float4*)emb;

  #pragma unroll
  for (int i = 0; i < 16; ++i) {
    const int g = tid + 256 * i, row = g >> 6, c4 = g & 63;
    float4 v = x4g[(size_t)(tok0 + row) * 64 + c4];
    float* p = &xs[row * 257 + c4 * 4];
    p[0] = v.x; p[1] = v.y; p[2] = v.z; p[3] = v.w;
  }
  if (tid < 64) As[tid] = oidx[tok0 + tid];   // A staged by vq_pre_a
  __syncthreads();

  const int t  = tid >> 2;
  const int j0 = tid & 3;
  const int gt = tok0 + t;
  const int cnt = cntG[gt];
  const float* xr = &xs[t * 257];
  const float  Ar = As[t];
  float best = 1e30f; int bid = 0x7FFFFFFF;

  auto eval = [&](int c) {
#pragma clang fp contract(off)
    const float4* er = e4g + (size_t)c * 64;
    float b = 0.0f;
    #pragma unroll 8
    for (int q = 0; q < 64; ++q) {        // exact ascending-k fmaf chain (R4)
      float4 ev = er[q];
      b = fmaf(xr[q * 4 + 0], ev.x, b);
      b = fmaf(xr[q * 4 + 1], ev.y, b);
      b = fmaf(xr[q * 4 + 2], ev.z, b);
      b = fmaf(xr[q * 4 + 3], ev.w, b);
    }
    const float t1 = fmaf(-2.0f, b, Ar);  // fl(A-2B)
    const float t2 = t1 + Cws[c];         // fl(.+C)
    if (t2 < best || (t2 == best && c < bid)) { best = t2; bid = c; }
  };

  if (cnt <= CAPC) {
    for (int j = j0; j < cnt; j += 4) eval(candG[(size_t)gt * CAPC + j]);
  } else {                                 // CAP overflow: exact full scan
    for (int c = j0; c < NCODES; c += 4) eval(c);
  }

  // combine 4 lanes per token; first-index (= min id) on ties
  #pragma unroll
  for (int off = 1; off <= 2; off <<= 1) {
    float ob = __shfl_xor(best, off);
    int   oi = __shfl_xor(bid, off);
    if (ob < best || (ob == best && oi < bid)) { best = ob; bid = oi; }
  }
  if (j0 == 0) { idx_sh[t] = bid; oidx[gt] = (float)(bid + 1); }
  __syncthreads();

  // gather y = emb[idx], accumulate loss
  float lsum = 0.0f;
  float4* y4 = (float4*)y;
  #pragma unroll
  for (int r = 0; r < 16; ++r) {
    const int g = tid + 256 * r, row = g >> 6, c4 = g & 63;
    const float4 ev = e4g[(size_t)idx_sh[row] * 64 + c4];
    const float4 xv = x4g[(size_t)(tok0 + row) * 64 + c4];
    y4[(size_t)(tok0 + row) * 64 + c4] = ev;
    const float dx = ev.x - xv.x, dy = ev.y - xv.y, dz = ev.z - xv.z, dw = ev.w - xv.w;
    lsum += dx * dx + dy * dy + dz * dz + dw * dw;
  }
  #pragma unroll
  for (int off = 32; off; off >>= 1) lsum += __shfl_down(lsum, off);
  if ((tid & 63) == 0) red[tid >> 6] = lsum;
  __syncthreads();
  if (tid == 0) atomicAdd(oloss, red[0] + red[1] + red[2] + red[3]);
}

__global__ void vq_fin(float* __restrict__ oloss) {
  *oloss = *oloss * (1.0f / 16777216.0f);
}

// ---------------- legacy R4 path (fallback if workspace too small) ----------------
__global__ __launch_bounds__(256, 2)
void vq_main(const float* __restrict__ x, const float* __restrict__ emb,
             const float* __restrict__ Cws, float* __restrict__ y,
             float* __restrict__ oidx, float* __restrict__ oloss) {
  __shared__ float4 xs4[TM * F4S];
  __shared__ float4 es4[TN * F4S];
  __shared__ float  Cs[TN];
  __shared__ int    idx_sh[TM];
  __shared__ float  red[4];

  const int tid = threadIdx.x;
  const int ry = tid >> 4;
  const int rx = tid & 15;
  const int tok0 = blockIdx.x * TM;

  const float4* x4g = (const float4*)x;
  const float4* e4g = (const float4*)emb;

  float A_reg[8];
  #pragma unroll
  for (int m = 0; m < 8; m++) A_reg[m] = oidx[tok0 + ry + 16 * m];

  float best[8];
  int   i1[8];
  #pragma unroll
  for (int m = 0; m < 8; m++) { best[m] = 1e30f; i1[m] = 0; }

  float acc[8][8];

  for (int seg = 0; seg < NSEG; ++seg) {
    const int chunk = seg >> 2;
    const int kq = seg & 3;
    __syncthreads();
    #pragma unroll
    for (int h = 0; h < 2; h++) {
      float4 t[4];
      #pragma unroll
      for (int q = 0; q < 4; q++) {
        const int r = h * 4 + q;
        t[q] = x4g[(size_t)(tok0 + ry + 16 * r) * 64 + kq * 16 + rx];
      }
      #pragma unroll
      for (int q = 0; q < 4; q++) {
        const int r = h * 4 + q;
        xs4[(ry + 16 * r) * F4S + rx] = t[q];
      }
    }
    #pragma unroll
    for (int h = 0; h < 2; h++) {
      float4 t[4];
      #pragma unroll
      for (int q = 0; q < 4; q++) {
        const int r = h * 4 + q;
        t[q] = e4g[(size_t)(chunk * TN + ry + 16 * r) * 64 + kq * 16 + rx];
      }
      #pragma unroll
      for (int q = 0; q < 4; q++) {
        const int r = h * 4 + q;
        es4[(ry + 16 * r) * F4S + rx] = t[q];
      }
    }
    if (kq == 0 && tid < TN) Cs[tid] = Cws[chunk * TN + tid];
    __syncthreads();

    if (kq == 0) {
      #pragma unroll
      for (int m = 0; m < 8; m++)
        #pragma unroll
        for (int n = 0; n < 8; n++) acc[m][n] = 0.0f;
    }

    #pragma unroll
    for (int k4 = 0; k4 < 16; k4++) {
      float4 a[8], b[8];
      #pragma unroll
      for (int m = 0; m < 8; m++) a[m] = xs4[(ry + 16 * m) * F4S + k4];
      #pragma unroll
      for (int n = 0; n < 8; n++) b[n] = es4[(rx + 16 * n) * F4S + k4];
      #pragma unroll
      for (int m = 0; m < 8; m++)
        #pragma unroll
        for (int n = 0; n < 8; n++) {
          acc[m][n] = fmaf(a[m].x, b[n].x, acc[m][n]);
          acc[m][n] = fmaf(a[m].y, b[n].y, acc[m][n]);
          acc[m][n] = fmaf(a[m].z, b[n].z, acc[m][n]);
          acc[m][n] = fmaf(a[m].w, b[n].w, acc[m][n]);
        }
    }

    if (kq == 3) {
      const int c0 = chunk * TN;
      #pragma unroll
      for (int n = 0; n < 8; n++) {
        const float Cv = Cs[rx + 16 * n];
        const int c = c0 + rx + 16 * n;
        #pragma unroll
        for (int m = 0; m < 8; m++) {
          const float t1 = fmaf(-2.0f, acc[m][n], A_reg[m]);
          const float t2 = t1 + Cv;
          if (t2 < best[m]) { best[m] = t2; i1[m] = c; }
        }
      }
    }
  }

  __syncthreads();
  float* bv1 = (float*)xs4;
  int*   bi  = (int*)es4;
  #pragma unroll
  for (int m = 0; m < 8; m++) {
    bv1[(ry + 16 * m) * 16 + rx] = best[m];
    bi [(ry + 16 * m) * 16 + rx] = i1[m];
  }
  __syncthreads();
  if (tid < TM) {
    float v = bv1[tid * 16];
    int   id = bi[tid * 16];
    for (int t = 1; t < 16; t++) {
      const float vv = bv1[tid * 16 + t];
      const int   ii = bi [tid * 16 + t];
      if (vv < v || (vv == v && ii < id)) { v = vv; id = ii; }
    }
    idx_sh[tid] = id;
    oidx[tok0 + tid] = (float)(id + 1);
  }
  __syncthreads();

  float lsum = 0.0f;
  float4* y4 = (float4*)y;
  #pragma unroll
  for (int r = 0; r < 32; r++) {
    const int g = tid + 256 * r, row = g >> 6, c4 = g & 63;
    const float4 ev = e4g[(size_t)idx_sh[row] * 64 + c4];
    const float4 xv = x4g[(size_t)(tok0 + row) * 64 + c4];
    y4[(size_t)(tok0 + row) * 64 + c4] = ev;
    const float dx = ev.x - xv.x, dy = ev.y - xv.y, dz = ev.z - xv.z, dw = ev.w - xv.w;
    lsum += dx * dx + dy * dy + dz * dz + dw * dw;
  }
  #pragma unroll
  for (int off = 32; off; off >>= 1) lsum += __shfl_down(lsum, off);
  if ((tid & 63) == 0) red[tid >> 6] = lsum;
  __syncthreads();
  if (tid == 0) atomicAdd(oloss, red[0] + red[1] + red[2] + red[3]);
}

extern "C" void kernel_launch(void* const* d_in, const int* in_sizes, int n_in,
                              void* d_out, int out_size, void* d_ws, size_t ws_size,
                              hipStream_t stream) {
  const float* x   = (const float*)d_in[0];   // [16,4096,256]
  const float* emb = (const float*)d_in[1];   // [8192,256]

  float* y     = (float*)d_out;               // [16,4096,256]
  float* oidx  = y + (size_t)BT * DDIM;       // [16,4096] idx channel
  float* oloss = oidx + BT;                   // [1]

  // workspace layout
  char*  wsB   = (char*)d_ws;
  float* Cws   = (float*)wsB;                         //  32 KiB
  int*   cntG  = (int*)(wsB + 32768);                 // 256 KiB
  char*  ebf   = wsB + 32768 + 262144;                //   4 MiB bf16 swizzled emb
  int*   candG = (int*)(wsB + 294912 + 4194304);      //  12 MiB candidate lists
  const size_t NEED = 294912 + 4194304 + (size_t)BT * CAPC * 4;  // 17072128 B

  vq_init <<<1, 1,           0, stream>>>(oloss);
  vq_pre_a<<<BT / 256, 256,  0, stream>>>(x, oidx);   // stage A in idx region
  vq_pre_c<<<NCODES/256,256, 0, stream>>>(emb, Cws);

  if (ws_size >= NEED) {
    vq_pre_e  <<<1024, 256, 0, stream>>>(emb, (uint4*)ebf);
    vq_filter <<<256,  512, 0, stream>>>(x, ebf, Cws, cntG, candG);
    vq_rescore<<<1024, 256, 0, stream>>>(x, emb, Cws, cntG, candG, y, oidx, oloss);
  } else {
    vq_main   <<<BT / TM, 256, 0, stream>>>(x, emb, Cws, y, oidx, oloss);
  }
  vq_fin  <<<1, 1,           0, stream>>>(oloss);
}

// Round 2
// 810.951 us; speedup vs baseline: 7.8843x; 7.8843x over previous
//
#include <hip/hip_runtime.h>
#include <stdint.h>

// VQ: bf16-MFMA candidate filter + exact np-fp32 rescore.
// Selection is bit-identical to the R4 kernel (absmax 32) as long as the
// exact winner lands in the candidate set: worst-case |s_tilde - s_exact|
// <= 5.9e-4 < MARGIN (7e-4). R6: overflow tokens (cnt>CAPC) are now handled
// by a cooperative 256-thread block scan instead of a 4-lane full scan that
// stalled whole blocks for ~1.5 ms (R5: rescore 6.3ms @ VALUBusy 3.9%).

#define NCODES 8192
#define DDIM   256
#define BT     65536

// legacy (R4) constants
#define TM     128
#define TN     128
#define NSEG   256
#define F4S    17

// new-path constants
#define CAPC   48
#define MARGIN 7e-4f          // proven bound 5.9e-4, headroom 1.19x
#define CHUNKS 64             // 8192 / 128 codes per chunk

typedef float  f32x4  __attribute__((ext_vector_type(4)));
typedef __bf16 bf16x8 __attribute__((ext_vector_type(8)));

#define GLDS16(g, l) __builtin_amdgcn_global_load_lds(                         \
    (const __attribute__((address_space(1))) void*)(g),                        \
    (__attribute__((address_space(3))) void*)(l), 16, 0, 0)
#define GLDS4(g, l) __builtin_amdgcn_global_load_lds(                          \
    (const __attribute__((address_space(1))) void*)(g),                        \
    (__attribute__((address_space(3))) void*)(l), 4, 0, 0)

// order-preserving float->uint map (for LDS atomicMin on scores)
__device__ __forceinline__ unsigned int fenc(float f) {
  unsigned int u = __float_as_uint(f);
  return (u & 0x80000000u) ? ~u : (u | 0x80000000u);
}
__device__ __forceinline__ float fdec(unsigned int u) {
  unsigned int v = (u & 0x80000000u) ? (u ^ 0x80000000u) : ~u;
  return __uint_as_float(v);
}

// numpy pairwise_sum (scalar path) for n=256 over p_i = fl32(x_i*x_i).
__device__ __forceinline__ float np_pairwise256_sq(const float4* __restrict__ row) {
#pragma clang fp contract(off)
  float half[2];
  #pragma unroll
  for (int h = 0; h < 2; h++) {
    float r0,r1,r2,r3,r4,r5,r6,r7;
    float4 q0 = row[h*32 + 0];
    float4 q1 = row[h*32 + 1];
    r0 = q0.x*q0.x; r1 = q0.y*q0.y; r2 = q0.z*q0.z; r3 = q0.w*q0.w;
    r4 = q1.x*q1.x; r5 = q1.y*q1.y; r6 = q1.z*q1.z; r7 = q1.w*q1.w;
    #pragma unroll
    for (int g = 1; g < 16; g++) {
      q0 = row[h*32 + g*2];
      q1 = row[h*32 + g*2 + 1];
      r0 += q0.x*q0.x; r1 += q0.y*q0.y; r2 += q0.z*q0.z; r3 += q0.w*q0.w;
      r4 += q1.x*q1.x; r5 += q1.y*q1.y; r6 += q1.z*q1.z; r7 += q1.w*q1.w;
    }
    half[h] = ((r0+r1) + (r2+r3)) + ((r4+r5) + (r6+r7));
  }
  return half[0] + half[1];
}

// exact R4 scoring chain: ascending-k fmaf, fl(A-2B), fl(.+C)
__device__ __forceinline__ float exact_score(const float* __restrict__ xr,
                                             const float4* __restrict__ er,
                                             float Ar, float Cv) {
#pragma clang fp contract(off)
  float b = 0.0f;
  #pragma unroll 8
  for (int q = 0; q < 64; ++q) {
    float4 ev = er[q];
    b = fmaf(xr[q * 4 + 0], ev.x, b);
    b = fmaf(xr[q * 4 + 1], ev.y, b);
    b = fmaf(xr[q * 4 + 2], ev.z, b);
    b = fmaf(xr[q * 4 + 3], ev.w, b);
  }
  const float t1 = fmaf(-2.0f, b, Ar);
  return t1 + Cv;
}

__global__ void vq_pre_a(const float* __restrict__ x, float* __restrict__ Astage) {
  const int t = blockIdx.x * 256 + threadIdx.x;
  Astage[t] = np_pairwise256_sq((const float4*)(x + (size_t)t * DDIM));
}

__global__ void vq_pre_c(const float* __restrict__ emb, float* __restrict__ Cws) {
  const int c = blockIdx.x * 256 + threadIdx.x;
  Cws[c] = np_pairwise256_sq((const float4*)(emb + (size_t)c * DDIM));
}

__global__ void vq_init(float* __restrict__ oloss) { *oloss = 0.0f; }

// emb fp32 -> bf16(RNE), stored XOR-swizzled so the filter's linear
// global_load_lds staging + swizzled ds_read_b128 is bank-conflict-free.
__global__ void vq_pre_e(const float* __restrict__ emb, uint4* __restrict__ ebf) {
  const int g   = blockIdx.x * 256 + threadIdx.x;   // 262144 total
  const int c   = g >> 5;
  const int blk = g & 31;
  const float4* e4 = (const float4*)(emb + (size_t)c * DDIM);
  float4 f0 = e4[blk*2], f1 = e4[blk*2 + 1];
  union { unsigned short us[8]; uint4 v; } pk;
  pk.us[0] = __builtin_bit_cast(unsigned short, (__bf16)f0.x);
  pk.us[1] = __builtin_bit_cast(unsigned short, (__bf16)f0.y);
  pk.us[2] = __builtin_bit_cast(unsigned short, (__bf16)f0.z);
  pk.us[3] = __builtin_bit_cast(unsigned short, (__bf16)f0.w);
  pk.us[4] = __builtin_bit_cast(unsigned short, (__bf16)f1.x);
  pk.us[5] = __builtin_bit_cast(unsigned short, (__bf16)f1.y);
  pk.us[6] = __builtin_bit_cast(unsigned short, (__bf16)f1.z);
  pk.us[7] = __builtin_bit_cast(unsigned short, (__bf16)f1.w);
  ebf[(size_t)c * 32 + (blk ^ (c & 7))] = pk.v;
}

__device__ __forceinline__ void stage_chunk(const char* __restrict__ ebf,
                                            const float* __restrict__ Cws,
                                            int ch, char* ebuf_dst,
                                            float* cs_dst, int tid) {
  const char* src = ebf + (size_t)ch * 65536 + (size_t)tid * 16;
  char* dst = ebuf_dst + (size_t)tid * 16;
  #pragma unroll
  for (int i = 0; i < 8; ++i) GLDS16(src + i * 8192, dst + i * 8192);
  if (tid < 128)
    GLDS4((const char*)Cws + (size_t)ch * 512 + (size_t)tid * 4,
          (char*)cs_dst + (size_t)tid * 4);
}

// ---------------- MFMA candidate filter ----------------
__global__ __launch_bounds__(512, 2)
void vq_filter(const float* __restrict__ x, const char* __restrict__ ebf,
               const float* __restrict__ Cws, int* __restrict__ cntG,
               int* __restrict__ candG) {
  __shared__ __align__(16) char ebuf[2][65536];   // 128 KiB double buffer
  __shared__ float Cs[3][128];                    // triple buffer (collect lags)
  __shared__ unsigned int umin[256];
  __shared__ int cntL[256];

  const int tid  = threadIdx.x;
  const int lane = tid & 63;
  const int wid  = tid >> 6;      // 0..7
  const int wm   = wid >> 2;      // 0..1  code half
  const int wn   = wid & 3;       // 0..3  token quarter
  const int l15  = lane & 15;
  const int lhi  = lane >> 4;     // 0..3
  const int tok0 = blockIdx.x * 256;

  if (tid < 256) { umin[tid] = 0xFFFFFFFFu; cntL[tid] = 0; }

  // stage chunk 0 (overlaps the x-fragment loads below)
  stage_chunk(ebf, Cws, 0, ebuf[0], Cs[0], tid);

  // B-frags: x[token][k] bf16, K-resident. frag reg j = k = kk*32 + lhi*8 + j.
  const float4* x4 = (const float4*)x;
  bf16x8 xb[4][8];
  #pragma unroll
  for (int n = 0; n < 4; ++n) {
    const size_t trow = (size_t)(tok0 + wn * 64 + n * 16 + l15) * 64;
    #pragma unroll
    for (int kk = 0; kk < 8; ++kk) {
      float4 f0 = x4[trow + kk * 8 + lhi * 2];
      float4 f1 = x4[trow + kk * 8 + lhi * 2 + 1];
      bf16x8 v;
      v[0] = (__bf16)f0.x; v[1] = (__bf16)f0.y; v[2] = (__bf16)f0.z; v[3] = (__bf16)f0.w;
      v[4] = (__bf16)f1.x; v[5] = (__bf16)f1.y; v[6] = (__bf16)f1.z; v[7] = (__bf16)f1.w;
      xb[n][kk] = v;
    }
  }
  __syncthreads();   // staging + init visible

  const f32x4 zf = {0.f, 0.f, 0.f, 0.f};

  for (int c = 0; c < CHUNKS; ++c) {
    // prefetch next chunk into the other buffers (wraps harmlessly at c=63)
    stage_chunk(ebf, Cws, (c + 1) & 63, ebuf[(c + 1) & 1], Cs[(c + 1) % 3], tid);

    const char* ecur = ebuf[c & 1];
    f32x4 acc[4][4];
    #pragma unroll
    for (int kk = 0; kk < 8; ++kk) {
      bf16x8 a[4];
      #pragma unroll
      for (int m = 0; m < 4; ++m) {
        const int row = wm * 64 + m * 16 + l15;
        const int blk = (kk * 4 + lhi) ^ (row & 7);
        a[m] = *(const bf16x8*)(ecur + row * 512 + blk * 16);
      }
      #pragma unroll
      for (int m = 0; m < 4; ++m)
        #pragma unroll
        for (int n = 0; n < 4; ++n)
          acc[m][n] = __builtin_amdgcn_mfma_f32_16x16x32_bf16(
              a[m], xb[n][kk], (kk == 0) ? zf : acc[m][n], 0, 0, 0);
    }

    // min phase: s~ = C - 2P, running per-token min via LDS atomicMin
    const float* Csc = Cs[c % 3];
    float cvals[4][4];
    #pragma unroll
    for (int m = 0; m < 4; ++m)
      #pragma unroll
      for (int r = 0; r < 4; ++r)
        cvals[m][r] = Csc[wm * 64 + m * 16 + lhi * 4 + r];

    #pragma unroll
    for (int n = 0; n < 4; ++n) {
      float mn = 1e30f;
      #pragma unroll
      for (int m = 0; m < 4; ++m)
        #pragma unroll
        for (int r = 0; r < 4; ++r)
          mn = fminf(mn, fmaf(-2.0f, acc[m][n][r], cvals[m][r]));
      atomicMin(&umin[wn * 64 + n * 16 + l15], fenc(mn));
    }

    __syncthreads();   // mins visible; next-chunk staging drained

    // collect phase: superset-safe (any observed umin >= final min)
    #pragma unroll
    for (int n = 0; n < 4; ++n) {
      const int t = wn * 64 + n * 16 + l15;
      const float thr = fdec(umin[t]) + MARGIN;
      #pragma unroll
      for (int m = 0; m < 4; ++m)
        #pragma unroll
        for (int r = 0; r < 4; ++r) {
          float s = fmaf(-2.0f, acc[m][n][r], cvals[m][r]);
          if (s <= thr) {
            int code = c * 128 + wm * 64 + m * 16 + lhi * 4 + r;
            int pos = atomicAdd(&cntL[t], 1);
            if (pos < CAPC) candG[(size_t)(tok0 + t) * CAPC + pos] = code;
          }
        }
    }
  }

  __syncthreads();
  if (tid < 256) cntG[tok0 + tid] = cntL[tid];
}

// ---------------- exact rescore + select + gather + loss ----------------
__global__ __launch_bounds__(256, 2)
void vq_rescore(const float* __restrict__ x, const float* __restrict__ emb,
                const float* __restrict__ Cws, const int* __restrict__ cntG,
                const int* __restrict__ candG, float* __restrict__ y,
                float* __restrict__ oidx, float* __restrict__ oloss) {
  __shared__ float xs[64 * 257];   // padded: chain reads conflict-free
  __shared__ float As[64];
  __shared__ int   idx_sh[64];
  __shared__ float red[4];
  __shared__ float rbv[256];       // cooperative-overflow argmin reduce
  __shared__ int   rbi[256];
  __shared__ int   ovf_list[64];
  __shared__ int   n_ovf;

  const int tid  = threadIdx.x;
  const int tok0 = blockIdx.x * 64;
  const float4* x4g = (const float4*)x;
  const float4* e4g = (const float4*)emb;

  if (tid == 0) n_ovf = 0;
  #pragma unroll
  for (int i = 0; i < 16; ++i) {
    const int g = tid + 256 * i, row = g >> 6, c4 = g & 63;
    float4 v = x4g[(size_t)(tok0 + row) * 64 + c4];
    float* p = &xs[row * 257 + c4 * 4];
    p[0] = v.x; p[1] = v.y; p[2] = v.z; p[3] = v.w;
  }
  if (tid < 64) As[tid] = oidx[tok0 + tid];   // A staged by vq_pre_a
  __syncthreads();

  const int t  = tid >> 2;
  const int j0 = tid & 3;
  const int gt = tok0 + t;
  const int cnt = cntG[gt];
  const float* xr = &xs[t * 257];
  const float  Ar = As[t];

  if (cnt <= CAPC) {
    // normal path: 4 lanes share the candidate list
    float best = 1e30f; int bid = 0x7FFFFFFF;
    for (int j = j0; j < cnt; j += 4) {
      const int c = candG[(size_t)gt * CAPC + j];
      const float s = exact_score(xr, e4g + (size_t)c * 64, Ar, Cws[c]);
      if (s < best || (s == best && c < bid)) { best = s; bid = c; }
    }
    #pragma unroll
    for (int off = 1; off <= 2; off <<= 1) {
      float ob = __shfl_xor(best, off);
      int   oi = __shfl_xor(bid, off);
      if (ob < best || (ob == best && oi < bid)) { best = ob; bid = oi; }
    }
    if (j0 == 0) { idx_sh[t] = bid; oidx[gt] = (float)(bid + 1); }
  } else if (j0 == 0) {            // rare: queue for cooperative scan
    const int p = atomicAdd(&n_ovf, 1);
    ovf_list[p] = t;
  }
  __syncthreads();                 // n_ovf/ovf_list visible to all

  // cooperative full scan for overflow tokens: 256 threads x 32 codes each
  for (int o = 0; o < n_ovf; ++o) {
    const int tt  = ovf_list[o];
    const float* xrr = &xs[tt * 257];
    const float  At  = As[tt];
    float bv = 1e30f; int bi2 = 0x7FFFFFFF;
    for (int c = tid; c < NCODES; c += 256) {
      const float s = exact_score(xrr, e4g + (size_t)c * 64, At, Cws[c]);
      if (s < bv || (s == bv && c < bi2)) { bv = s; bi2 = c; }
    }
    rbv[tid] = bv; rbi[tid] = bi2;
    __syncthreads();
    #pragma unroll
    for (int sft = 128; sft; sft >>= 1) {
      if (tid < sft) {
        const float v2 = rbv[tid + sft]; const int i2 = rbi[tid + sft];
        if (v2 < rbv[tid] || (v2 == rbv[tid] && i2 < rbi[tid])) {
          rbv[tid] = v2; rbi[tid] = i2;
        }
      }
      __syncthreads();
    }
    if (tid == 0) { idx_sh[tt] = rbi[0]; oidx[tok0 + tt] = (float)(rbi[0] + 1); }
    __syncthreads();               // rbv/rbi reuse next iteration
  }
  __syncthreads();                 // idx_sh complete

  // gather y = emb[idx], accumulate loss
  float lsum = 0.0f;
  float4* y4 = (float4*)y;
  #pragma unroll
  for (int r = 0; r < 16; ++r) {
    const int g = tid + 256 * r, row = g >> 6, c4 = g & 63;
    const float4 ev = e4g[(size_t)idx_sh[row] * 64 + c4];
    const float4 xv = x4g[(size_t)(tok0 + row) * 64 + c4];
    y4[(size_t)(tok0 + row) * 64 + c4] = ev;
    const float dx = ev.x - xv.x, dy = ev.y - xv.y, dz = ev.z - xv.z, dw = ev.w - xv.w;
    lsum += dx * dx + dy * dy + dz * dz + dw * dw;
  }
  #pragma unroll
  for (int off = 32; off; off >>= 1) lsum += __shfl_down(lsum, off);
  if ((tid & 63) == 0) red[tid >> 6] = lsum;
  __syncthreads();
  if (tid == 0) atomicAdd(oloss, red[0] + red[1] + red[2] + red[3]);
}

__global__ void vq_fin(float* __restrict__ oloss) {
  *oloss = *oloss * (1.0f / 16777216.0f);
}

// ---------------- legacy R4 path (fallback if workspace too small) ----------------
__global__ __launch_bounds__(256, 2)
void vq_main(const float* __restrict__ x, const float* __restrict__ emb,
             const float* __restrict__ Cws, float* __restrict__ y,
             float* __restrict__ oidx, float* __restrict__ oloss) {
  __shared__ float4 xs4[TM * F4S];
  __shared__ float4 es4[TN * F4S];
  __shared__ float  Cs[TN];
  __shared__ int    idx_sh[TM];
  __shared__ float  red[4];

  const int tid = threadIdx.x;
  const int ry = tid >> 4;
  const int rx = tid & 15;
  const int tok0 = blockIdx.x * TM;

  const float4* x4g = (const float4*)x;
  const float4* e4g = (const float4*)emb;

  float A_reg[8];
  #pragma unroll
  for (int m = 0; m < 8; m++) A_reg[m] = oidx[tok0 + ry + 16 * m];

  float best[8];
  int   i1[8];
  #pragma unroll
  for (int m = 0; m < 8; m++) { best[m] = 1e30f; i1[m] = 0; }

  float acc[8][8];

  for (int seg = 0; seg < NSEG; ++seg) {
    const int chunk = seg >> 2;
    const int kq = seg & 3;
    __syncthreads();
    #pragma unroll
    for (int h = 0; h < 2; h++) {
      float4 t[4];
      #pragma unroll
      for (int q = 0; q < 4; q++) {
        const int r = h * 4 + q;
        t[q] = x4g[(size_t)(tok0 + ry + 16 * r) * 64 + kq * 16 + rx];
      }
      #pragma unroll
      for (int q = 0; q < 4; q++) {
        const int r = h * 4 + q;
        xs4[(ry + 16 * r) * F4S + rx] = t[q];
      }
    }
    #pragma unroll
    for (int h = 0; h < 2; h++) {
      float4 t[4];
      #pragma unroll
      for (int q = 0; q < 4; q++) {
        const int r = h * 4 + q;
        t[q] = e4g[(size_t)(chunk * TN + ry + 16 * r) * 64 + kq * 16 + rx];
      }
      #pragma unroll
      for (int q = 0; q < 4; q++) {
        const int r = h * 4 + q;
        es4[(ry + 16 * r) * F4S + rx] = t[q];
      }
    }
    if (kq == 0 && tid < TN) Cs[tid] = Cws[chunk * TN + tid];
    __syncthreads();

    if (kq == 0) {
      #pragma unroll
      for (int m = 0; m < 8; m++)
        #pragma unroll
        for (int n = 0; n < 8; n++) acc[m][n] = 0.0f;
    }

    #pragma unroll
    for (int k4 = 0; k4 < 16; k4++) {
      float4 a[8], b[8];
      #pragma unroll
      for (int m = 0; m < 8; m++) a[m] = xs4[(ry + 16 * m) * F4S + k4];
      #pragma unroll
      for (int n = 0; n < 8; n++) b[n] = es4[(rx + 16 * n) * F4S + k4];
      #pragma unroll
      for (int m = 0; m < 8; m++)
        #pragma unroll
        for (int n = 0; n < 8; n++) {
          acc[m][n] = fmaf(a[m].x, b[n].x, acc[m][n]);
          acc[m][n] = fmaf(a[m].y, b[n].y, acc[m][n]);
          acc[m][n] = fmaf(a[m].z, b[n].z, acc[m][n]);
          acc[m][n] = fmaf(a[m].w, b[n].w, acc[m][n]);
        }
    }

    if (kq == 3) {
      const int c0 = chunk * TN;
      #pragma unroll
      for (int n = 0; n < 8; n++) {
        const float Cv = Cs[rx + 16 * n];
        const int c = c0 + rx + 16 * n;
        #pragma unroll
        for (int m = 0; m < 8; m++) {
          const float t1 = fmaf(-2.0f, acc[m][n], A_reg[m]);
          const float t2 = t1 + Cv;
          if (t2 < best[m]) { best[m] = t2; i1[m] = c; }
        }
      }
    }
  }

  __syncthreads();
  float* bv1 = (float*)xs4;
  int*   bi  = (int*)es4;
  #pragma unroll
  for (int m = 0; m < 8; m++) {
    bv1[(ry + 16 * m) * 16 + rx] = best[m];
    bi [(ry + 16 * m) * 16 + rx] = i1[m];
  }
  __syncthreads();
  if (tid < TM) {
    float v = bv1[tid * 16];
    int   id = bi[tid * 16];
    for (int t = 1; t < 16; t++) {
      const float vv = bv1[tid * 16 + t];
      const int   ii = bi [tid * 16 + t];
      if (vv < v || (vv == v && ii < id)) { v = vv; id = ii; }
    }
    idx_sh[tid] = id;
    oidx[tok0 + tid] = (float)(id + 1);
  }
  __syncthreads();

  float lsum = 0.0f;
  float4* y4 = (float4*)y;
  #pragma unroll
  for (int r = 0; r < 32; r++) {
    const int g = tid + 256 * r, row = g >> 6, c4 = g & 63;
    const float4 ev = e4g[(size_t)idx_sh[row] * 64 + c4];
    const float4 xv = x4g[(size_t)(tok0 + row) * 64 + c4];
    y4[(size_t)(tok0 + row) * 64 + c4] = ev;
    const float dx = ev.x - xv.x, dy = ev.y - xv.y, dz = ev.z - xv.z, dw = ev.w - xv.w;
    lsum += dx * dx + dy * dy + dz * dz + dw * dw;
  }
  #pragma unroll
  for (int off = 32; off; off >>= 1) lsum += __shfl_down(lsum, off);
  if ((tid & 63) == 0) red[tid >> 6] = lsum;
  __syncthreads();
  if (tid == 0) atomicAdd(oloss, red[0] + red[1] + red[2] + red[3]);
}

extern "C" void kernel_launch(void* const* d_in, const int* in_sizes, int n_in,
                              void* d_out, int out_size, void* d_ws, size_t ws_size,
                              hipStream_t stream) {
  const float* x   = (const float*)d_in[0];   // [16,4096,256]
  const float* emb = (const float*)d_in[1];   // [8192,256]

  float* y     = (float*)d_out;               // [16,4096,256]
  float* oidx  = y + (size_t)BT * DDIM;       // [16,4096] idx channel
  float* oloss = oidx + BT;                   // [1]

  // workspace layout
  char*  wsB   = (char*)d_ws;
  float* Cws   = (float*)wsB;                         //  32 KiB
  int*   cntG  = (int*)(wsB + 32768);                 // 256 KiB
  char*  ebf   = wsB + 32768 + 262144;                //   4 MiB bf16 swizzled emb
  int*   candG = (int*)(wsB + 294912 + 4194304);      //  12 MiB candidate lists
  const size_t NEED = 294912 + 4194304 + (size_t)BT * CAPC * 4;  // 17072128 B

  vq_init <<<1, 1,           0, stream>>>(oloss);
  vq_pre_a<<<BT / 256, 256,  0, stream>>>(x, oidx);   // stage A in idx region
  vq_pre_c<<<NCODES/256,256, 0, stream>>>(emb, Cws);

  if (ws_size >= NEED) {
    vq_pre_e  <<<1024, 256, 0, stream>>>(emb, (uint4*)ebf);
    vq_filter <<<256,  512, 0, stream>>>(x, ebf, Cws, cntG, candG);
    vq_rescore<<<1024, 256, 0, stream>>>(x, emb, Cws, cntG, candG, y, oidx, oloss);
  } else {
    vq_main   <<<BT / TM, 256, 0, stream>>>(x, emb, Cws, y, oidx, oloss);
  }
  vq_fin  <<<1, 1,           0, stream>>>(oloss);
}